// Round 3
// baseline (272.430 us; speedup 1.0000x reference)
//
#include <hip/hip_runtime.h>
#include <math.h>

#define S 4096
#define QK_SCALE 0.17677669529663687f  // 1/sqrt(32)
#define LOG2E    1.44269504088896f
#define SPLIT 4
#define KS (S / SPLIT)                 // 1024 keys per split

typedef _Float16 f16x8 __attribute__((ext_vector_type(8)));
typedef _Float16 f16x4 __attribute__((ext_vector_type(4)));
typedef _Float16 f16x2 __attribute__((ext_vector_type(2)));
typedef float f32x4 __attribute__((ext_vector_type(4)));

// ---------------------------------------------------------------------------
// MFMA lane map (HW-verified R4): A-frag m=l&15, k=(l>>4)*8+j; B-frag n=l&15;
// C reg r: row=(l>>4)*4+r, col=l&15.
// R12: wo_ln_merge + ffn_pair + reduce8_ln fused into ONE layer_tail kernel
// (grid 256 = 1 block/CU): merge->Wo->LN1(fp32 regs)->W1 stream->relu->Fh
// ->W2 full-K=1024 fp32 acc->LN2. Kills 16MB/layer wpart round-trip + 2
// dispatches/layer. attn SPLIT 8->4 (halves apart traffic). 12 dispatches.
// LDS strides: 136 f16 = 68 dw == 4 (mod 32) banks; Fh 1032 f16 = 516 dw
// == 4 (mod 32) -> same balanced b128 pattern.
// ---------------------------------------------------------------------------
template<int R>
__device__ __forceinline__ void stageT(_Float16 (*dst)[136], const _Float16* __restrict__ src,
                                       int ld, int row0, int col0, int tid) {
    int r = tid >> 4, cb = (tid & 15) * 8;   // 16 rows x 128 cols per pass, coalesced
#pragma unroll
    for (int v = 0; v < R / 16; v++)
        *(f16x8*)&dst[v * 16 + r][cb] =
            *(const f16x8*)(src + (size_t)(row0 + v * 16 + r) * ld + col0 + cb);
}

// prefetch-to-regs / write-to-LDS split of stageT<128> (async-split staging)
__device__ __forceinline__ void ldT128(f16x8 pf[8], const _Float16* __restrict__ src,
                                       int ld, int row0, int col0, int tid) {
    int r = tid >> 4, cb = (tid & 15) * 8;
#pragma unroll
    for (int v = 0; v < 8; v++)
        pf[v] = *(const f16x8*)(src + (size_t)(row0 + v * 16 + r) * ld + col0 + cb);
}
__device__ __forceinline__ void stT128(_Float16 (*dst)[136], const f16x8 pf[8], int tid) {
    int r = tid >> 4, cb = (tid & 15) * 8;
#pragma unroll
    for (int v = 0; v < 8; v++)
        *(f16x8*)&dst[v * 16 + r][cb] = pf[v];
}

// ---------------------------------------------------------------------------
// setup: weight fp32->fp16 conversion (blocks 0..991) + x/xh copy (992..1503).
// ---------------------------------------------------------------------------
__global__ __launch_bounds__(256) void setup_cvt(const float* __restrict__ q,
                                                 const float* __restrict__ wo,
                                                 const float* __restrict__ w1,
                                                 const float* __restrict__ w2,
                                                 const float* __restrict__ f1,
                                                 const float* __restrict__ f2,
                                                 _Float16* __restrict__ dst,
                                                 const float* __restrict__ a,
                                                 float* __restrict__ x,
                                                 _Float16* __restrict__ xh)
{
    int bb = blockIdx.x;
    if (bb < 992) {
        const float* src; size_t dof; int lb;
        if (bb < 144)      { src = q;  dof = 0;      lb = bb; }
        else if (bb < 192) { src = wo; dof = 147456; lb = bb - 144; }
        else if (bb < 576) { src = w1; dof = 196608; lb = bb - 192; }
        else if (bb < 960) { src = w2; dof = 589824; lb = bb - 576; }
        else if (bb < 976) { src = f1; dof = 983040; lb = bb - 960; }
        else               { src = f2; dof = 999424; lb = bb - 976; }
        int i = lb * 1024 + threadIdx.x * 4;
        float4 v = *(const float4*)(src + i);
        f16x4 h = {(_Float16)v.x, (_Float16)v.y, (_Float16)v.z, (_Float16)v.w};
        *(f16x4*)(dst + dof + i) = h;
    } else {
        int i = (bb - 992) * 256 + threadIdx.x;
        float4 v = ((const float4*)a)[i];
        ((float4*)x)[i] = v;
        f16x4 h = {(_Float16)v.x, (_Float16)v.y, (_Float16)v.z, (_Float16)v.w};
        ((f16x4*)xh)[i] = h;
    }
}

// ---------------------------------------------------------------------------
// QKV GEMM, 16-row tiles, full-K single barrier. grid (256, 3).
// ---------------------------------------------------------------------------
__global__ __launch_bounds__(256) void gemm_qkv(const _Float16* __restrict__ xh,
                                                const _Float16* __restrict__ Wh,
                                                const float* __restrict__ bias,
                                                _Float16* __restrict__ qh,
                                                _Float16* __restrict__ kh,
                                                _Float16* __restrict__ vt)
{
    __shared__ _Float16 Ah[16][136], Bh[128][136];
    int tid = threadIdx.x, w = tid >> 6, l = tid & 63, lc = l & 15, lr = l >> 4;
    int m0 = blockIdx.x * 16, by = blockIdx.y;

    stageT<16>(Ah, xh, 128, m0, 0, tid);
    stageT<128>(Bh, Wh, 128, by * 128, 0, tid);
    __syncthreads();

    f32x4 acc[2];
#pragma unroll
    for (int j = 0; j < 2; j++) acc[j] = {0.f, 0.f, 0.f, 0.f};
#pragma unroll
    for (int ks = 0; ks < 4; ks++) {
        f16x8 af = *(const f16x8*)&Ah[lc][ks * 32 + lr * 8];
#pragma unroll
        for (int j = 0; j < 2; j++) {
            f16x8 bf = *(const f16x8*)&Bh[w * 32 + j * 16 + lc][ks * 32 + lr * 8];
            acc[j] = __builtin_amdgcn_mfma_f32_16x16x32_f16(af, bf, acc[j], 0, 0, 0);
        }
    }

    int mb = m0 + lr * 4;
#pragma unroll
    for (int j = 0; j < 2; j++) {
        int n = w * 32 + j * 16 + lc;
        float bb = bias[by * 128 + n];
        if (by == 0) {
#pragma unroll
            for (int r = 0; r < 4; r++)
                qh[(size_t)(mb + r) * 128 + n] =
                    (_Float16)((acc[j][r] + bb) * (QK_SCALE * LOG2E));
        } else if (by == 1) {
            int hh = n >> 5, d = n & 31;
#pragma unroll
            for (int r = 0; r < 4; r++)
                kh[((size_t)hh * S + mb + r) * 32 + d] = (_Float16)(acc[j][r] + bb);
        } else {
            f16x4 pk;
#pragma unroll
            for (int r = 0; r < 4; r++) pk[r] = (_Float16)(acc[j][r] + bb);
            *(f16x4*)&vt[(size_t)n * S + mb] = pk;
        }
    }
}

// ---------------------------------------------------------------------------
// MFMA flash attention: K/V double-buffer, async-split staging, one barrier
// per tile; swapped QK^T (C[k][q]) -> packed Ps writes + 2-shfl l-reduce.
// SPLIT=4: 16 tiles/block, 1024 blocks (4/CU).
// ---------------------------------------------------------------------------
__global__ __launch_bounds__(256) void attn_mfma(const _Float16* __restrict__ qh,
                                                 const _Float16* __restrict__ kh,
                                                 const _Float16* __restrict__ vt,
                                                 _Float16* __restrict__ part,
                                                 float* __restrict__ mll)
{
    __shared__ _Float16 Ks[2][64][32];
    __shared__ _Float16 Vt[2][32][72];
    __shared__ _Float16 Ps[4][16][72];
    int h = blockIdx.y, q0 = blockIdx.x * 64, z = blockIdx.z;
    int tid = threadIdx.x;
    int w = tid >> 6, l = tid & 63;
    int lc = l & 15, lr = l >> 4;

    f16x8 qf = *(const f16x8*)&qh[(size_t)(q0 + w * 16 + lc) * 128 + h * 32 + lr * 8];

    const _Float16* khh = kh + (size_t)h * S * 32;
    const _Float16* vth = vt + (size_t)h * 32 * S;

    int krow = tid >> 2, kcol = (tid & 3) * 8;
    int vrow = tid >> 3, vcol = (tid & 7) * 8;

    f32x4 o0 = {0.f, 0.f, 0.f, 0.f}, o1 = {0.f, 0.f, 0.f, 0.f};
    float lp = 0.f;

    int k0 = z * KS;
    {   // prologue: stage tile 0
        f16x8 kr = *(const f16x8*)&khh[(size_t)(k0 + krow) * 32 + kcol];
        f16x8 vr = *(const f16x8*)&vth[(size_t)vrow * S + k0 + vcol];
        *(f16x8*)&Ks[0][krow][kcol] = kr;
        *(f16x8*)&Vt[0][vrow][vcol] = vr;
    }
    __syncthreads();

    int cur = 0;
#pragma unroll 1
    for (int t8 = 0; t8 < KS / 64; t8++) {
        bool more = (t8 + 1 < KS / 64);
        f16x8 kr, vr;
        if (more) {   // issue next tile's loads early; latency hides under compute
            int kn = k0 + (t8 + 1) * 64;
            kr = *(const f16x8*)&khh[(size_t)(kn + krow) * 32 + kcol];
            vr = *(const f16x8*)&vth[(size_t)vrow * S + kn + vcol];
        }

        f32x4 st[4];
        __builtin_amdgcn_s_setprio(1);
#pragma unroll
        for (int t = 0; t < 4; t++) {
            f16x8 kf = *(const f16x8*)&Ks[cur][t * 16 + lc][lr * 8];
            f32x4 zz = {0.f, 0.f, 0.f, 0.f};
            st[t] = __builtin_amdgcn_mfma_f32_16x16x32_f16(kf, qf, zz, 0, 0, 0);
        }
        __builtin_amdgcn_s_setprio(0);
#pragma unroll
        for (int t = 0; t < 4; t++) {
            float p0 = exp2f(st[t][0]), p1 = exp2f(st[t][1]);
            float p2 = exp2f(st[t][2]), p3 = exp2f(st[t][3]);
            lp += (p0 + p1) + (p2 + p3);
            f16x2 h0 = {(_Float16)p0, (_Float16)p1};
            f16x2 h1 = {(_Float16)p2, (_Float16)p3};
            *(f16x2*)&Ps[w][lc][t * 16 + lr * 4]     = h0;
            *(f16x2*)&Ps[w][lc][t * 16 + lr * 4 + 2] = h1;
        }
        asm volatile("s_waitcnt lgkmcnt(0)" ::: "memory");
        __builtin_amdgcn_s_setprio(1);
#pragma unroll
        for (int ch = 0; ch < 2; ch++) {
            f16x8 pf = *(const f16x8*)&Ps[w][lc][ch * 32 + lr * 8];
            f16x8 v0 = *(const f16x8*)&Vt[cur][lc][ch * 32 + lr * 8];
            f16x8 v1 = *(const f16x8*)&Vt[cur][16 + lc][ch * 32 + lr * 8];
            o0 = __builtin_amdgcn_mfma_f32_16x16x32_f16(pf, v0, o0, 0, 0, 0);
            o1 = __builtin_amdgcn_mfma_f32_16x16x32_f16(pf, v1, o1, 0, 0, 0);
        }
        __builtin_amdgcn_s_setprio(0);
        if (more) {
            *(f16x8*)&Ks[cur ^ 1][krow][kcol] = kr;
            *(f16x8*)&Vt[cur ^ 1][vrow][vcol] = vr;
            __syncthreads();
        }
        cur ^= 1;
    }

    lp += __shfl_xor(lp, 16);
    lp += __shfl_xor(lp, 32);

    _Float16* pz = part + (size_t)z * 524288;
#pragma unroll
    for (int i = 0; i < 4; i++) {
        int q = q0 + w * 16 + lr * 4 + i;
        pz[(size_t)q * 128 + h * 32 + lc]      = (_Float16)o0[i];
        pz[(size_t)q * 128 + h * 32 + 16 + lc] = (_Float16)o1[i];
    }
    if (l < 16) mll[((size_t)z * 4 + h) * 4096 + q0 + w * 16 + lc] = lp;
}

// ---------------------------------------------------------------------------
// layer_tail: attention-merge + Wo + bias + residual + LN1 (fp32 regs) +
// W1(relu) + W2 (full K=1024, fp32 acc) + b2 + LN1-residual + LN2 -> x, xh.
// grid 256 (1 block/CU), 16-row tiles. W1/W2 streamed in 8x32KB chunks,
// double-buffered via reg-prefetch, one barrier per chunk.
// ---------------------------------------------------------------------------
__global__ __launch_bounds__(256) void layer_tail(const _Float16* __restrict__ part,
                                                  const float* __restrict__ mll,
                                                  const _Float16* __restrict__ Woh,
                                                  const float* __restrict__ bo,
                                                  const _Float16* __restrict__ W1h,
                                                  const float* __restrict__ b1,
                                                  const _Float16* __restrict__ W2h,
                                                  const float* __restrict__ b2,
                                                  const float* __restrict__ g1,
                                                  const float* __restrict__ bn1,
                                                  const float* __restrict__ g2,
                                                  const float* __restrict__ bn2,
                                                  float* __restrict__ x,
                                                  _Float16* __restrict__ xh)
{
    __shared__ _Float16 Ah[16][136];        // merged attn, then LN1 output
    __shared__ _Float16 Bh[2][128][136];    // streamed weight chunks (dbuf)
    __shared__ _Float16 Fh[16][1032];       // relu(x@W1^T+b1), 516 dw == 4 mod 32
    __shared__ float Red[16][4][2];
    int tid = threadIdx.x, w = tid >> 6, l = tid & 63, lc = l & 15, lr = l >> 4;
    int m0 = blockIdx.x * 16;

    {   // merge-stage A: 16 rows x 128 cols, 8 cols/thread
        int row = tid >> 4, col0 = (tid & 15) * 8;
        int q = m0 + row, hh = col0 >> 5;
        float lsum = 0.f;
#pragma unroll
        for (int s = 0; s < SPLIT; s++) lsum += mll[((size_t)s * 4 + hh) * 4096 + q];
        float am[8];
#pragma unroll
        for (int e = 0; e < 8; e++) am[e] = 0.f;
#pragma unroll
        for (int s = 0; s < SPLIT; s++) {
            f16x8 t = *(const f16x8*)&part[(size_t)s * 524288 + (size_t)q * 128 + col0];
#pragma unroll
            for (int e = 0; e < 8; e++) am[e] += (float)t[e];
        }
        float inv = 1.f / lsum;
        f16x8 hv;
#pragma unroll
        for (int e = 0; e < 8; e++) hv[e] = (_Float16)(am[e] * inv);
        *(f16x8*)&Ah[row][col0] = hv;
    }
    stageT<128>(Bh[0], Woh, 128, 0, 0, tid);
    __syncthreads();

    // residual loads issued early (consumed after Wo MFMA)
    float xv[2][4];
#pragma unroll
    for (int j = 0; j < 2; j++)
#pragma unroll
        for (int r = 0; r < 4; r++)
            xv[j][r] = x[(size_t)(m0 + lr * 4 + r) * 128 + w * 32 + j * 16 + lc];

    // Wo GEMM, K=128
    f32x4 acc[2];
#pragma unroll
    for (int j = 0; j < 2; j++) acc[j] = {0.f, 0.f, 0.f, 0.f};
#pragma unroll
    for (int ks = 0; ks < 4; ks++) {
        f16x8 af = *(const f16x8*)&Ah[lc][ks * 32 + lr * 8];
#pragma unroll
        for (int j = 0; j < 2; j++) {
            f16x8 bf = *(const f16x8*)&Bh[0][w * 32 + j * 16 + lc][ks * 32 + lr * 8];
            acc[j] = __builtin_amdgcn_mfma_f32_16x16x32_f16(af, bf, acc[j], 0, 0, 0);
        }
    }

    // prefetch W1 chunk 0 while LN1 runs
    f16x8 pf[8];
    ldT128(pf, W1h, 128, 0, 0, tid);

#pragma unroll
    for (int j = 0; j < 2; j++) {
        int n = w * 32 + j * 16 + lc;
        float bb = bo[n];
#pragma unroll
        for (int r = 0; r < 4; r++) acc[j][r] += bb + xv[j][r];
    }
    // LN1 stats (per-wave 32-col partials -> Red -> combine)
#pragma unroll
    for (int r = 0; r < 4; r++) {
        float s1 = acc[0][r] + acc[1][r];
        float s2 = acc[0][r] * acc[0][r] + acc[1][r] * acc[1][r];
#pragma unroll
        for (int off = 1; off < 16; off <<= 1) {
            s1 += __shfl_xor(s1, off);
            s2 += __shfl_xor(s2, off);
        }
        if (lc == 0) { Red[lr * 4 + r][w][0] = s1; Red[lr * 4 + r][w][1] = s2; }
    }
    __syncthreads();   // Red ready; also: all Wo MFMA reads of Ah/Bh[0] done

    float ln1v[2][4];
#pragma unroll
    for (int r = 0; r < 4; r++) {
        int rl = lr * 4 + r;
        float S1 = (Red[rl][0][0] + Red[rl][1][0]) + (Red[rl][2][0] + Red[rl][3][0]);
        float S2 = (Red[rl][0][1] + Red[rl][1][1]) + (Red[rl][2][1] + Red[rl][3][1]);
        float mean = S1 * (1.0f / 128.0f);
        float var = S2 * (1.0f / 128.0f) - mean * mean;
        float inv = rsqrtf(var + 1e-5f);
#pragma unroll
        for (int j = 0; j < 2; j++) {
            int n = w * 32 + j * 16 + lc;
            ln1v[j][r] = (acc[j][r] - mean) * inv * g1[n] + bn1[n];
            Ah[rl][n] = (_Float16)ln1v[j][r];     // LN1 out -> A-layout LDS
        }
    }
    stT128(Bh[1], pf, tid);                       // W1 chunk 0 -> LDS
    __syncthreads();                              // Ah + Bh[1] visible

    // ---- W1 loop: F = relu(LN1 @ W1^T + b1), 8 chunks of 128 FF-cols ----
    int cur = 1;
#pragma unroll 1
    for (int c = 0; c < 8; c++) {
        if (c < 7) ldT128(pf, W1h, 128, (c + 1) * 128, 0, tid);
        else       ldT128(pf, W2h, 1024, 0, 0, tid);      // W2 chunk 0
        f32x4 fa[2];
#pragma unroll
        for (int j = 0; j < 2; j++) fa[j] = {0.f, 0.f, 0.f, 0.f};
#pragma unroll
        for (int ks = 0; ks < 4; ks++) {
            f16x8 af = *(const f16x8*)&Ah[lc][ks * 32 + lr * 8];
#pragma unroll
            for (int j = 0; j < 2; j++) {
                f16x8 bf = *(const f16x8*)&Bh[cur][w * 32 + j * 16 + lc][ks * 32 + lr * 8];
                fa[j] = __builtin_amdgcn_mfma_f32_16x16x32_f16(af, bf, fa[j], 0, 0, 0);
            }
        }
#pragma unroll
        for (int j = 0; j < 2; j++) {
            int n = w * 32 + j * 16 + lc;
            float bb = b1[c * 128 + n];
#pragma unroll
            for (int r = 0; r < 4; r++)
                Fh[lr * 4 + r][c * 128 + n] = (_Float16)fmaxf(fa[j][r] + bb, 0.f);
        }
        stT128(Bh[cur ^ 1], pf, tid);   // safe: reads of Bh[cur^1] done (prev barrier)
        __syncthreads();                // next chunk + this Fh slice visible
        cur ^= 1;
    }

    // ---- W2 loop: o = F @ W2^T, K=1024 in fp32 accumulators ----
    f32x4 oacc[2];
#pragma unroll
    for (int j = 0; j < 2; j++) oacc[j] = {0.f, 0.f, 0.f, 0.f};
#pragma unroll 1
    for (int c = 0; c < 8; c++) {
        if (c < 7) ldT128(pf, W2h, 1024, 0, (c + 1) * 128, tid);
#pragma unroll
        for (int ks = 0; ks < 4; ks++) {
            f16x8 af = *(const f16x8*)&Fh[lc][c * 128 + ks * 32 + lr * 8];
#pragma unroll
            for (int j = 0; j < 2; j++) {
                f16x8 bf = *(const f16x8*)&Bh[cur][w * 32 + j * 16 + lc][ks * 32 + lr * 8];
                oacc[j] = __builtin_amdgcn_mfma_f32_16x16x32_f16(af, bf, oacc[j], 0, 0, 0);
            }
        }
        if (c < 7) {
            stT128(Bh[cur ^ 1], pf, tid);
            __syncthreads();
            cur ^= 1;
        }
    }

    // ---- b2 + LN1 residual + LN2 -> x, xh ----
#pragma unroll
    for (int j = 0; j < 2; j++) {
        int n = w * 32 + j * 16 + lc;
        float bb = b2[n];
#pragma unroll
        for (int r = 0; r < 4; r++) oacc[j][r] += bb + ln1v[j][r];
    }
#pragma unroll
    for (int r = 0; r < 4; r++) {
        float s1 = oacc[0][r] + oacc[1][r];
        float s2 = oacc[0][r] * oacc[0][r] + oacc[1][r] * oacc[1][r];
#pragma unroll
        for (int off = 1; off < 16; off <<= 1) {
            s1 += __shfl_xor(s1, off);
            s2 += __shfl_xor(s2, off);
        }
        if (lc == 0) { Red[lr * 4 + r][w][0] = s1; Red[lr * 4 + r][w][1] = s2; }
    }
    __syncthreads();
#pragma unroll
    for (int r = 0; r < 4; r++) {
        int rl = lr * 4 + r;
        float S1 = (Red[rl][0][0] + Red[rl][1][0]) + (Red[rl][2][0] + Red[rl][3][0]);
        float S2 = (Red[rl][0][1] + Red[rl][1][1]) + (Red[rl][2][1] + Red[rl][3][1]);
        float mean = S1 * (1.0f / 128.0f);
        float var = S2 * (1.0f / 128.0f) - mean * mean;
        float inv = rsqrtf(var + 1e-5f);
        int m = m0 + rl;
#pragma unroll
        for (int j = 0; j < 2; j++) {
            int n = w * 32 + j * 16 + lc;
            float o = (oacc[j][r] - mean) * inv * g2[n] + bn2[n];
            x[(size_t)m * 128 + n] = o;
            xh[(size_t)m * 128 + n] = (_Float16)o;
        }
    }
}

// ---------------------------------------------------------------------------
// fc1 + relu + fc2 + rownorm fused. 16-row tiles, grid 256.
// ---------------------------------------------------------------------------
__global__ __launch_bounds__(256) void fc_fused(const _Float16* __restrict__ xh,
                                                const _Float16* __restrict__ W1h,
                                                const float* __restrict__ b1f,
                                                const _Float16* __restrict__ W2h,
                                                const float* __restrict__ b2f,
                                                _Float16* __restrict__ aoh)
{
    __shared__ _Float16 Ah[16][136], Bh[128][136];
    __shared__ float Red[16][4];
    int tid = threadIdx.x, w = tid >> 6, l = tid & 63, lc = l & 15, lr = l >> 4;
    int m0 = blockIdx.x * 16;

    stageT<16>(Ah, xh, 128, m0, 0, tid);
    stageT<128>(Bh, W1h, 128, 0, 0, tid);
    __syncthreads();

    f32x4 acc[2];
#pragma unroll
    for (int j = 0; j < 2; j++) acc[j] = {0.f, 0.f, 0.f, 0.f};
#pragma unroll
    for (int ks = 0; ks < 4; ks++) {
        f16x8 af = *(const f16x8*)&Ah[lc][ks * 32 + lr * 8];
#pragma unroll
        for (int j = 0; j < 2; j++) {
            f16x8 bf = *(const f16x8*)&Bh[w * 32 + j * 16 + lc][ks * 32 + lr * 8];
            acc[j] = __builtin_amdgcn_mfma_f32_16x16x32_f16(af, bf, acc[j], 0, 0, 0);
        }
    }
    __syncthreads();
#pragma unroll
    for (int j = 0; j < 2; j++) {
        int n = w * 32 + j * 16 + lc;
        float bb = b1f[n];
#pragma unroll
        for (int r = 0; r < 4; r++)
            Ah[lr * 4 + r][n] = (_Float16)fmaxf(acc[j][r] + bb, 0.f);
    }
    stageT<128>(Bh, W2h, 128, 0, 0, tid);
    __syncthreads();

    f32x4 o[2];
#pragma unroll
    for (int j = 0; j < 2; j++) o[j] = {0.f, 0.f, 0.f, 0.f};
#pragma unroll
    for (int ks = 0; ks < 4; ks++) {
        f16x8 af = *(const f16x8*)&Ah[lc][ks * 32 + lr * 8];
#pragma unroll
        for (int j = 0; j < 2; j++) {
            f16x8 bf = *(const f16x8*)&Bh[w * 32 + j * 16 + lc][ks * 32 + lr * 8];
            o[j] = __builtin_amdgcn_mfma_f32_16x16x32_f16(af, bf, o[j], 0, 0, 0);
        }
    }
#pragma unroll
    for (int j = 0; j < 2; j++) {
        float bb = b2f[w * 32 + j * 16 + lc];
#pragma unroll
        for (int r = 0; r < 4; r++) o[j][r] += bb;
    }
#pragma unroll
    for (int r = 0; r < 4; r++) {
        float s2 = o[0][r] * o[0][r] + o[1][r] * o[1][r];
#pragma unroll
        for (int off = 1; off < 16; off <<= 1) s2 += __shfl_xor(s2, off);
        if (lc == 0) Red[lr * 4 + r][w] = s2;
    }
    __syncthreads();
#pragma unroll
    for (int r = 0; r < 4; r++) {
        int rl = lr * 4 + r;
        float inv = rsqrtf((Red[rl][0] + Red[rl][1]) + (Red[rl][2] + Red[rl][3]));
        int m = m0 + rl;
#pragma unroll
        for (int j = 0; j < 2; j++) {
            int n = w * 32 + j * 16 + lc;
            aoh[(size_t)m * 128 + n] = (_Float16)(o[j][r] * inv);
        }
    }
}

// ---------------------------------------------------------------------------
// Gram: C = max(aoh @ aoh^T, 1e-6). 64x128 tiles, full-K single barrier,
// grid (64, 32) = 2048 blocks.
// ---------------------------------------------------------------------------
__global__ __launch_bounds__(256) void gram_f16(const _Float16* __restrict__ aoh,
                                                float* __restrict__ C)
{
    __shared__ _Float16 Ah[64][136], Bh[128][136];
    int tid = threadIdx.x, w = tid >> 6, l = tid & 63, lc = l & 15, lr = l >> 4;
    int wr = w >> 1, wc = w & 1;
    int m0 = blockIdx.x * 64, n0 = blockIdx.y * 128;

    stageT<64>(Ah, aoh, 128, m0, 0, tid);
    stageT<128>(Bh, aoh, 128, n0, 0, tid);
    __syncthreads();

    f32x4 acc[2][4];
#pragma unroll
    for (int i = 0; i < 2; i++)
#pragma unroll
        for (int j = 0; j < 4; j++) acc[i][j] = {0.f, 0.f, 0.f, 0.f};
#pragma unroll
    for (int ks = 0; ks < 4; ks++) {
        f16x8 af0 = *(const f16x8*)&Ah[wr * 32 + lc][ks * 32 + lr * 8];
        f16x8 af1 = *(const f16x8*)&Ah[wr * 32 + 16 + lc][ks * 32 + lr * 8];
#pragma unroll
        for (int j = 0; j < 4; j++) {
            f16x8 bf = *(const f16x8*)&Bh[wc * 64 + j * 16 + lc][ks * 32 + lr * 8];
            acc[0][j] = __builtin_amdgcn_mfma_f32_16x16x32_f16(af0, bf, acc[0][j], 0, 0, 0);
            acc[1][j] = __builtin_amdgcn_mfma_f32_16x16x32_f16(af1, bf, acc[1][j], 0, 0, 0);
        }
    }

#pragma unroll
    for (int i = 0; i < 2; i++) {
        int mb = m0 + wr * 32 + i * 16 + lr * 4;
#pragma unroll
        for (int j = 0; j < 4; j++) {
            int n = n0 + wc * 64 + j * 16 + lc;
#pragma unroll
            for (int r = 0; r < 4; r++)
                C[(size_t)(mb + r) * 4096 + n] = fmaxf(acc[i][j][r], 1e-6f);
        }
    }
}

// ---------------------------------------------------------------------------
extern "C" void kernel_launch(void* const* d_in, const int* in_sizes, int n_in,
                              void* d_out, int out_size, void* d_ws, size_t ws_size,
                              hipStream_t stream)
{
    const float* src  = (const float*)d_in[0];
    const float* Wqkv = (const float*)d_in[1];
    const float* bqkv = (const float*)d_in[2];
    const float* Wo   = (const float*)d_in[3];
    const float* bo   = (const float*)d_in[4];
    const float* ln1g = (const float*)d_in[5];
    const float* ln1b = (const float*)d_in[6];
    const float* W1   = (const float*)d_in[7];
    const float* b1   = (const float*)d_in[8];
    const float* W2   = (const float*)d_in[9];
    const float* b2   = (const float*)d_in[10];
    const float* ln2g = (const float*)d_in[11];
    const float* ln2b = (const float*)d_in[12];
    const float* fc1W = (const float*)d_in[13];
    const float* fc1b = (const float*)d_in[14];
    const float* fc2W = (const float*)d_in[15];
    const float* fc2b = (const float*)d_in[16];

    float* ws = (float*)d_ws;
    float*    x   = ws;                                   // 524288 f32
    _Float16* xh  = (_Float16*)(ws + 524288);             // 524288 f16
    _Float16* aoh = (_Float16*)(ws + 786432);             // 524288 f16
    _Float16* qh  = (_Float16*)(ws + 1048576);            // 524288 f16
    _Float16* kh  = (_Float16*)(ws + 1310720);            // 524288 f16
    _Float16* vt  = (_Float16*)(ws + 1572864);            // 524288 f16
    float*    mll = ws + 1835008;                         // 65536 f32 (SPLIT=4)

    // d_out scratch (all dead before gram writes):
    _Float16* apart = (_Float16*)d_out + 12582912;        // bytes [24MiB,28MiB) SPLIT=4
    _Float16* wh    = (_Float16*)d_out + 16777216;        // bytes [32MiB,~34MiB)
    float*    out   = (float*)d_out;

    _Float16* qkvh = wh;                  // 3 x 384 x 128
    _Float16* woh  = wh + 147456;         // 3 x 128 x 128
    _Float16* w1h  = wh + 196608;         // 3 x 1024 x 128
    _Float16* w2h  = wh + 589824;         // 3 x 128 x 1024
    _Float16* fc1h = wh + 983040;         // 128 x 128
    _Float16* fc2h = wh + 999424;         // 128 x 128

    setup_cvt<<<1504, 256, 0, stream>>>(Wqkv, Wo, W1, W2, fc1W, fc2W, wh,
                                        src, x, xh);
    for (int l = 0; l < 3; l++) {
        gemm_qkv<<<dim3(256, 3), 256, 0, stream>>>(xh, qkvh + l * 49152,
                                                   bqkv + l * 384, qh, kh, vt);
        attn_mfma<<<dim3(64, 4, SPLIT), 256, 0, stream>>>(qh, kh, vt, apart, mll);
        layer_tail<<<256, 256, 0, stream>>>(apart, mll, woh + l * 16384, bo + l * 128,
                                            w1h + l * 131072, b1 + l * 1024,
                                            w2h + l * 131072, b2 + l * 128,
                                            ln1g + l * 128, ln1b + l * 128,
                                            ln2g + l * 128, ln2b + l * 128, x, xh);
    }
    fc_fused<<<256, 256, 0, stream>>>(xh, fc1h, fc1b, fc2h, fc2b, aoh);
    gram_f16<<<dim3(64, 32), 256, 0, stream>>>(aoh, out);
}